// Round 1
// baseline (199.066 us; speedup 1.0000x reference)
//
#include <hip/hip_runtime.h>
#include <math.h>

#define BB 8
#define DD 256
#define NN 2048
#define NH 4
#define DH 64

typedef _Float16 half8   __attribute__((ext_vector_type(8)));
typedef _Float16 half4_t __attribute__((ext_vector_type(4)));
typedef _Float16 half2_t __attribute__((ext_vector_type(2)));
typedef float    floatx4 __attribute__((ext_vector_type(4)));

#define MFMA32(A, B, C) __builtin_amdgcn_mfma_f32_16x16x32_f16(A, B, C, 0, 0, 0)

// softmax scale folded into Q: 0.125 * log2(e)
#define SC 0.18033688011112042f

// ---------------------------------------------------------------------------
// Weight prep: cast wq/wk/wv to f16 natural [cout][k]; wm permuted k:
// wmf[cout][h*64+d] = wm[cout][4d+h]  (attn-out channel order = h*64+d).
// ---------------------------------------------------------------------------
__global__ __launch_bounds__(256) void prep_weights(
    const float* __restrict__ wq, const float* __restrict__ wk,
    const float* __restrict__ wv, const float* __restrict__ wm,
    _Float16* __restrict__ wqf, _Float16* __restrict__ wkf,
    _Float16* __restrict__ wvf, _Float16* __restrict__ wmf)
{
    int id = blockIdx.x * 256 + threadIdx.x;   // 0..65535
    wqf[id] = (_Float16)wq[id];
    wkf[id] = (_Float16)wk[id];
    wvf[id] = (_Float16)wv[id];
    int row = id >> 8, col = id & 255;
    int hh = col >> 6, dd = col & 63;
    wmf[id] = (_Float16)wm[row * 256 + dd * 4 + hh];
}

// ===========================================================================
// Conv: weights-in-registers. Block 256 thr (4 waves), tile 128 cout x 64 n,
// K = 256. Wave w holds its 32-cout x 256-k W slice as A-frags in 64 VGPRs
// (loaded once). X staged once to LDS [n 64][k 256] pitch 264; k-loop is
// barrier-free and has NO global loads: 8 ds_read_b128 x 4 nt -> 64 MFMA.
// ===========================================================================

// ---------------------------------------------------------------------------
// Fused Q/K/V projections. grid (32, 8, 6): z = tensor*2 + cout-half.
// Q,K out: f16 Y[(b*4+h)*2048+n][d]  (cout = 4d+h; Q scaled by SC)
// V   out: f16 Y[((b*4+h)*64+d)][n]
// ---------------------------------------------------------------------------
__global__ __launch_bounds__(256, 3) void conv_qkv(
    const _Float16* __restrict__ wqf, const _Float16* __restrict__ wkf,
    const _Float16* __restrict__ wvf,
    const float* __restrict__ bq, const float* __restrict__ bk,
    const float* __restrict__ bv,
    const float* __restrict__ Xq, const float* __restrict__ Xk,
    const float* __restrict__ Xv,
    _Float16* __restrict__ Yq, _Float16* __restrict__ Yk,
    _Float16* __restrict__ Yv)
{
    const int n0 = blockIdx.x * 64;
    const int b  = blockIdx.y;
    const int zh = blockIdx.z;
    const int z  = zh >> 1;
    const int hf = zh & 1;          // cout half
    const _Float16* Wf = z == 0 ? wqf : (z == 1 ? wkf : wvf);
    const float* bias  = z == 0 ? bq  : (z == 1 ? bk  : bv);
    const float* X     = z == 0 ? Xq  : (z == 1 ? Xk  : Xv);
    const float osc    = z == 0 ? SC : 1.0f;
    const int cout0 = hf * 128;

    const int t = threadIdx.x;
    const int w = t >> 6, l = t & 63, c = l & 15, q = l >> 4;

    __shared__ _Float16 smem[64 * 264];   // 33.8 KB

    // weight A-frags, loaded once: wave w owns couts cout0 + w*32 .. +32
    half8 af[2][8];
    {
        const _Float16* wp = Wf + (size_t)(cout0 + w * 32 + c) * 256 + q * 8;
        #pragma unroll
        for (int rt = 0; rt < 2; ++rt)
            #pragma unroll
            for (int ch = 0; ch < 8; ++ch)
                af[rt][ch] = *(const half8*)(wp + rt * 16 * 256 + ch * 32);
    }

    // stage X fp32 [k][n] -> LDS f16 [n][k], 4 chunks of 64 k
    {
        const int nb = t & 15, kb = t >> 4;
        #pragma unroll
        for (int cc = 0; cc < 4; ++cc) {
            const float* Xg = X + (size_t)b * DD * NN +
                              (size_t)(cc * 64 + kb * 4) * NN + n0 + nb * 4;
            float4 x[4];
            #pragma unroll
            for (int i = 0; i < 4; ++i) x[i] = *(const float4*)(Xg + (size_t)i * NN);
            #pragma unroll
            for (int j = 0; j < 4; ++j) {
                half4_t hv;
                #pragma unroll
                for (int i = 0; i < 4; ++i) hv[i] = (_Float16)(((const float*)&x[i])[j]);
                *(half4_t*)(smem + (nb * 4 + j) * 264 + cc * 64 + kb * 4) = hv;
            }
        }
    }
    __syncthreads();

    floatx4 acc[2][4];
    #pragma unroll
    for (int rt = 0; rt < 2; ++rt)
        #pragma unroll
        for (int nt = 0; nt < 4; ++nt) acc[rt][nt] = (floatx4){0.f, 0.f, 0.f, 0.f};

    #pragma unroll
    for (int ch = 0; ch < 8; ++ch)
        #pragma unroll
        for (int nt = 0; nt < 4; ++nt) {
            half8 bx = *(const half8*)(smem + (nt * 16 + c) * 264 + ch * 32 + q * 8);
            acc[0][nt] = MFMA32(af[0][ch], bx, acc[0][nt]);
            acc[1][nt] = MFMA32(af[1][ch], bx, acc[1][nt]);
        }

    if (z < 2) {
        // stage [n 64][cl 128] pitch 136, gather 32-d runs per (n, h)
        __syncthreads();
        #pragma unroll
        for (int rt = 0; rt < 2; ++rt)
            #pragma unroll
            for (int nt = 0; nt < 4; ++nt) {
                half4_t hv;
                #pragma unroll
                for (int r = 0; r < 4; ++r)
                    hv[r] = (_Float16)((acc[rt][nt][r] +
                            bias[cout0 + w * 32 + rt * 16 + q * 4 + r]) * osc);
                *(half4_t*)(smem + (nt * 16 + c) * 136 + w * 32 + rt * 16 + q * 4) = hv;
            }
        __syncthreads();
        _Float16* Y = z == 0 ? Yq : Yk;
        const int nn = t >> 2, hh = t & 3;
        half8 hv[4];
        #pragma unroll
        for (int i = 0; i < 4; ++i)
            #pragma unroll
            for (int k = 0; k < 8; ++k)
                hv[i][k] = smem[nn * 136 + (i * 8 + k) * 4 + hh];
        _Float16* dst = Y + ((size_t)(b * NH + hh) * NN + n0 + nn) * 64 + hf * 32;
        #pragma unroll
        for (int i = 0; i < 4; ++i) *(half8*)(dst + i * 8) = hv[i];
    } else {
        // stage [cl 128][n 64] pitch 72, row-write per cout
        __syncthreads();
        #pragma unroll
        for (int rt = 0; rt < 2; ++rt)
            #pragma unroll
            for (int nt = 0; nt < 4; ++nt)
                #pragma unroll
                for (int r = 0; r < 4; ++r)
                    smem[(w * 32 + rt * 16 + q * 4 + r) * 72 + nt * 16 + c] =
                        (_Float16)(acc[rt][nt][r] +
                                   bias[cout0 + w * 32 + rt * 16 + q * 4 + r]);
        __syncthreads();
        const int cl = t >> 1, noff = (t & 1) * 32;
        const int cout = cout0 + cl;
        const int hh = cout & 3, dd = cout >> 2;
        _Float16* dst = Yv + ((size_t)(b * NH + hh) * 64 + dd) * NN + n0 + noff;
        #pragma unroll
        for (int i = 0; i < 4; ++i)
            *(half8*)(dst + i * 8) = *(const half8*)(smem + cl * 72 + noff + i * 8);
    }
}

// ---------------------------------------------------------------------------
// Final projection: weights in regs, B-frags DIRECT from global At[n][256]
// (natural half8s, no LDS staging). Output fp32 [b][cout][n].
// grid (32, 8, 2): z = cout half.
// ---------------------------------------------------------------------------
__global__ __launch_bounds__(256, 3) void conv_o(
    const _Float16* __restrict__ Wf, const float* __restrict__ bias,
    const _Float16* __restrict__ At, float* __restrict__ out)
{
    const int n0 = blockIdx.x * 64;
    const int b  = blockIdx.y;
    const int hf = blockIdx.z;
    const int cout0 = hf * 128;

    const int t = threadIdx.x;
    const int w = t >> 6, l = t & 63, c = l & 15, q = l >> 4;

    __shared__ float fs[128 * 66];   // 33.8 KB

    half8 af[2][8];
    {
        const _Float16* wp = Wf + (size_t)(cout0 + w * 32 + c) * 256 + q * 8;
        #pragma unroll
        for (int rt = 0; rt < 2; ++rt)
            #pragma unroll
            for (int ch = 0; ch < 8; ++ch)
                af[rt][ch] = *(const half8*)(wp + rt * 16 * 256 + ch * 32);
    }

    floatx4 acc[2][4];
    #pragma unroll
    for (int rt = 0; rt < 2; ++rt)
        #pragma unroll
        for (int nt = 0; nt < 4; ++nt) acc[rt][nt] = (floatx4){0.f, 0.f, 0.f, 0.f};

    #pragma unroll
    for (int ch = 0; ch < 8; ++ch)
        #pragma unroll
        for (int nt = 0; nt < 4; ++nt) {
            half8 bx = *(const half8*)(At +
                ((size_t)b * NN + n0 + nt * 16 + c) * 256 + ch * 32 + q * 8);
            acc[0][nt] = MFMA32(af[0][ch], bx, acc[0][nt]);
            acc[1][nt] = MFMA32(af[1][ch], bx, acc[1][nt]);
        }

    #pragma unroll
    for (int rt = 0; rt < 2; ++rt)
        #pragma unroll
        for (int nt = 0; nt < 4; ++nt)
            #pragma unroll
            for (int r = 0; r < 4; ++r)
                fs[(w * 32 + rt * 16 + q * 4 + r) * 66 + nt * 16 + c] =
                    acc[rt][nt][r] + bias[cout0 + w * 32 + rt * 16 + q * 4 + r];
    __syncthreads();
    const int cl = t >> 1, noff = (t & 1) * 32;
    float* dst = out + (size_t)b * DD * NN + (size_t)(cout0 + cl) * NN + n0 + noff;
    #pragma unroll
    for (int i = 0; i < 8; ++i)
        *(float4*)(dst + i * 4) = *(const float4*)(fs + cl * 66 + noff + i * 4);
}

// ---------------------------------------------------------------------------
// MFMA flash attention, FULL m per block (no split, no partials). 512 thr =
// 8 waves x 16 q-cols; q-tile 128; 16 iterations of 128 m.
// S^T = K^T Q (16x16x32). PV: ONE 16x16x32 MFMA per (dt, mt2) via the
// sigma-permuted V column order kappa(m) = 32(m>>5)+8((m>>2)&3)+4((m>>4)&1)
// +(m&3); B = concat(p0,p1). After the loop every lane holds the full row
// sum lp for its q-column (two shfl_xor), so normalization is fused here
// and f16 At[b][n][h*64+d] is written directly — no Op/Lp round-trip, no
// combine kernel. grid (16, 4, 8) = 512 blocks = 2 blocks/CU (same
// residency as before at ~100 VGPR: the old 4-blocks/CU goal needed
// <=64 VGPR and never happened).
// ---------------------------------------------------------------------------
__global__ __launch_bounds__(512) void attn_mfma6(
    const _Float16* __restrict__ Qt, const _Float16* __restrict__ Kt,
    const _Float16* __restrict__ V, _Float16* __restrict__ At)
{
    const int n0 = blockIdx.x * 128;
    const int h  = blockIdx.y;
    const int b  = blockIdx.z;
    const int t  = threadIdx.x;
    const int w  = t >> 6, l = t & 63, c = l & 15, q = l >> 4;

    const size_t bh = (size_t)(b * NH + h);

    __shared__ _Float16 smem[9216 + 8704];   // 35.8 KB
    _Float16* Ks = smem;            // [m 128][d 64] pitch 72
    _Float16* Vs = smem + 9216;     // [d 64][kappa(m) 128] pitch 136

    half8 bq2[2];
    #pragma unroll
    for (int ch = 0; ch < 2; ++ch)
        bq2[ch] = *(const half8*)(Qt + (bh * NN + n0 + w * 16 + c) * 64 + ch * 32 + q * 8);

    float lp = 0.f;
    floatx4 o[4];
    #pragma unroll
    for (int dt = 0; dt < 4; ++dt) o[dt] = (floatx4){0.f, 0.f, 0.f, 0.f};

    const int ksr = t >> 2, ksc = (t & 3) * 16;
    const int vr  = t >> 3, vcb = (t & 7) * 16;
    const _Float16* Kg = Kt + bh * NN * 64;   // [m][d]
    const _Float16* Vg = V + bh * 64 * NN;    // [d][n]

    half8 kpre[2], vpre[2];
    kpre[0] = *(const half8*)(Kg + (size_t)ksr * 64 + ksc);
    kpre[1] = *(const half8*)(Kg + (size_t)ksr * 64 + ksc + 8);
    vpre[0] = *(const half8*)(Vg + (size_t)vr * NN + vcb);
    vpre[1] = *(const half8*)(Vg + (size_t)vr * NN + vcb + 8);

    for (int m0 = 0; m0 < NN; m0 += 128) {
        __syncthreads();
        *(half8*)(Ks + ksr * 72 + ksc)     = kpre[0];
        *(half8*)(Ks + ksr * 72 + ksc + 8) = kpre[1];
        #pragma unroll
        for (int u = 0; u < 2; ++u) {
            const int mb = vcb + u * 8;
            const int p0 = (mb & ~31) + (((mb >> 2) & 3) << 3) + (((mb >> 4) & 1) << 2);
            half4_t lo, hi;
            #pragma unroll
            for (int j = 0; j < 4; ++j) { lo[j] = vpre[u][j]; hi[j] = vpre[u][4 + j]; }
            *(half4_t*)(Vs + vr * 136 + p0)     = lo;
            *(half4_t*)(Vs + vr * 136 + p0 + 8) = hi;
        }
        __syncthreads();

        const int mn = (m0 + 128 < NN) ? m0 + 128 : m0;
        kpre[0] = *(const half8*)(Kg + (size_t)(mn + ksr) * 64 + ksc);
        kpre[1] = *(const half8*)(Kg + (size_t)(mn + ksr) * 64 + ksc + 8);
        vpre[0] = *(const half8*)(Vg + (size_t)vr * NN + mn + vcb);
        vpre[1] = *(const half8*)(Vg + (size_t)vr * NN + mn + vcb + 8);

        #pragma unroll
        for (int mt2 = 0; mt2 < 4; ++mt2) {
            half8 p8;
            #pragma unroll
            for (int hfm = 0; hfm < 2; ++hfm) {
                const int mt = mt2 * 2 + hfm;
                floatx4 s = {0.f, 0.f, 0.f, 0.f};
                #pragma unroll
                for (int ch = 0; ch < 2; ++ch) {
                    half8 ak = *(const half8*)(Ks + (mt * 16 + c) * 72 + ch * 32 + q * 8);
                    s = MFMA32(ak, bq2[ch], s);
                }
                float e0 = exp2f(s[0]), e1 = exp2f(s[1]);
                float e2 = exp2f(s[2]), e3 = exp2f(s[3]);
                lp += (e0 + e1) + (e2 + e3);
                half2_t c01 = __builtin_bit_cast(half2_t, __builtin_amdgcn_cvt_pkrtz(e0, e1));
                half2_t c23 = __builtin_bit_cast(half2_t, __builtin_amdgcn_cvt_pkrtz(e2, e3));
                p8[hfm * 4 + 0] = c01[0]; p8[hfm * 4 + 1] = c01[1];
                p8[hfm * 4 + 2] = c23[0]; p8[hfm * 4 + 3] = c23[1];
            }
            #pragma unroll
            for (int dt = 0; dt < 4; ++dt) {
                half8 av = *(const half8*)(Vs + (dt * 16 + c) * 136 + mt2 * 32 + q * 8);
                o[dt] = MFMA32(av, p8, o[dt]);
            }
        }
    }

    // full row-sum for this lane's q-column (sum over the 4 q-groups)
    lp += __shfl_xor(lp, 16);
    lp += __shfl_xor(lp, 32);
    const float inv = 1.f / lp;

    // stage normalized f16 O and write At[b][n][h*64+d] directly
    __syncthreads();
    _Float16* fsm = smem;            // [n 128][d 64] pitch 72
    #pragma unroll
    for (int dt = 0; dt < 4; ++dt) {
        half4_t hv;
        #pragma unroll
        for (int r = 0; r < 4; ++r) hv[r] = (_Float16)(o[dt][r] * inv);
        *(half4_t*)(fsm + (w * 16 + c) * 72 + dt * 16 + q * 4) = hv;
    }
    __syncthreads();
    const int rn = t >> 2, seg = (t & 3) * 16;
    _Float16* dst = At + ((size_t)b * NN + n0 + rn) * 256 + h * 64 + seg;
    *(half8*)(dst)     = *(const half8*)(fsm + rn * 72 + seg);
    *(half8*)(dst + 8) = *(const half8*)(fsm + rn * 72 + seg + 8);
}

extern "C" void kernel_launch(void* const* d_in, const int* in_sizes, int n_in,
                              void* d_out, int out_size, void* d_ws, size_t ws_size,
                              hipStream_t stream) {
    const float* query = (const float*)d_in[0];
    const float* key_  = (const float*)d_in[1];
    const float* value = (const float*)d_in[2];
    const float* wq    = (const float*)d_in[3];
    const float* bq    = (const float*)d_in[4];
    const float* wk    = (const float*)d_in[5];
    const float* bk    = (const float*)d_in[6];
    const float* wv    = (const float*)d_in[7];
    const float* bv    = (const float*)d_in[8];
    const float* wm    = (const float*)d_in[9];
    const float* bm    = (const float*)d_in[10];
    float* out = (float*)d_out;

    _Float16* ws = (_Float16*)d_ws;
    _Float16* wqf = ws;
    _Float16* wkf = wqf + 65536;
    _Float16* wvf = wkf + 65536;
    _Float16* wmf = wvf + 65536;
    const size_t e16 = (size_t)BB * NH * NN * DH;   // 4,194,304
    _Float16* qf = ws + 262144;
    _Float16* kf = qf + e16;
    _Float16* vf = kf + e16;
    _Float16* at = vf + e16;   // own buffer: attn reads qf while writing At

    prep_weights<<<256, 256, 0, stream>>>(wq, wk, wv, wm, wqf, wkf, wvf, wmf);
    conv_qkv<<<dim3(32, 8, 6), 256, 0, stream>>>(wqf, wkf, wvf, bq, bk, bv,
                                                 query, key_, value, qf, kf, vf);
    attn_mfma6<<<dim3(16, 4, 8), 512, 0, stream>>>(qf, kf, vf, at);
    conv_o<<<dim3(32, 8, 2), 256, 0, stream>>>(wmf, bm, at, out);
}